// Round 5
// baseline (488.403 us; speedup 1.0000x reference)
//
#include <hip/hip_runtime.h>
#include <hip/hip_bf16.h>
#include <math.h>

#define BB 4
#define CC 128
#define HH 128
#define WW 128
#define HWs 16384
#define GG 8
#define OMCH 216

typedef __bf16 bf16_t;
typedef bf16_t bf16x8 __attribute__((ext_vector_type(8)));
typedef float f32x4 __attribute__((ext_vector_type(4)));

// ---------------- prep: weight rearrange ----------------
// wpack1   MFMA A-frag bf16 W_off: [ks8][ot8][lane][8], o=ot*16+(lane&15), c=ks*32+(lane>>4)*8+r
// wpack    MFMA A-frag bf16 W_om:  [ks=cblk*9+tap][ot16][lane][8]
// wpdcn    MFMA A-frag bf16 W_dcn: [g][ks5][ot8][lane][8], K=ks*32+(lane>>4)*8+r -> (tap=K>>4, c''=K&15), 0 for K>=144
__global__ __launch_bounds__(256) void k_prep(const float* __restrict__ W_off,
                                              const float* __restrict__ W_om,
                                              const float* __restrict__ W_dcn,
                                              bf16_t* __restrict__ wpack1,
                                              bf16_t* __restrict__ wpack,
                                              bf16_t* __restrict__ wpdcn) {
    int idx = blockIdx.x * 256 + threadIdx.x;
    if (idx < 4096) {
        int j = idx;
        int lane = j & 63;
        int rest = j >> 6;       // 0..63
        int ot = rest & 7;
        int ks = rest >> 3;      // 0..7
        int o = ot * 16 + (lane & 15);
        int cbase = ks * 32 + ((lane >> 4) << 3);
        bf16x8 v;
        #pragma unroll
        for (int r = 0; r < 8; ++r) v[r] = (bf16_t)W_off[o * 256 + cbase + r];
        *((bf16x8*)wpack1 + j) = v;
    } else if (idx < 4096 + 36864) {
        int j = idx - 4096;
        int lane = j & 63;
        int rest = j >> 6;       // 0..575
        int ot = rest & 15;
        int ks = rest >> 4;      // 0..35
        int cblk = ks / 9, tap = ks % 9;
        int o = ot * 16 + (lane & 15);
        int cbase = cblk * 32 + ((lane >> 4) << 3);
        bf16x8 v;
        #pragma unroll
        for (int r = 0; r < 8; ++r) {
            float x = (o < OMCH) ? W_om[((o * 128 + cbase + r) * 9) + tap] : 0.0f;
            v[r] = (bf16_t)x;
        }
        *((bf16x8*)wpack + j) = v;
    } else if (idx < 4096 + 36864 + 20480) {
        int j = idx - 40960;
        int lane = j & 63;
        int rest = j >> 6;       // 0..319
        int ot = rest & 7;
        int gks = rest >> 3;     // 0..39
        int g = gks / 5, ks = gks % 5;
        int o = ot * 16 + (lane & 15);
        int Kbase = ks * 32 + ((lane >> 4) << 3);
        bf16x8 v;
        #pragma unroll
        for (int r = 0; r < 8; ++r) {
            int K = Kbase + r;
            float x = 0.0f;
            if (K < 144) {
                int tap = K >> 4, cpp = K & 15;
                x = W_dcn[((o * 128) + g * 16 + cpp) * 9 + tap];
            }
            v[r] = (bf16_t)x;
        }
        *((bf16x8*)wpdcn + j) = v;
    }
}

// ---------------- bilinear 2x upsample ----------------
__global__ __launch_bounds__(256) void k_upsample(const float* __restrict__ fs,
                                                  float* __restrict__ fu) {
    int idx = blockIdx.x * 256 + threadIdx.x;
    int x = idx & 127, y = (idx >> 7) & 127, bc = idx >> 14;
    int j = y >> 1, i = x >> 1;
    int ya, yb; float wya, wyb;
    if (y & 1) { ya = j; yb = (j < 63) ? j + 1 : 63; wya = 0.75f; wyb = 0.25f; }
    else       { ya = (j > 0) ? j - 1 : 0; yb = j;   wya = 0.25f; wyb = 0.75f; }
    int xa, xb; float wxa, wxb;
    if (x & 1) { xa = i; xb = (i < 63) ? i + 1 : 63; wxa = 0.75f; wxb = 0.25f; }
    else       { xa = (i > 0) ? i - 1 : 0; xb = i;   wxa = 0.25f; wxb = 0.75f; }
    const float* p = fs + (size_t)bc * 4096;
    float v = wya * (wxa * p[ya * 64 + xa] + wxb * p[ya * 64 + xb])
            + wyb * (wxa * p[yb * 64 + xa] + wxb * p[yb * 64 + xb]);
    fu[idx] = v;
}

// ---------------- 1x1 conv via MFMA ----------------
// Block: 64 pos x 128 outs, 4 waves; wave w owns o-tiles {2w,2w+1} x 4 p-tiles. K=256, 8 steps.
#define X1LD 264
__global__ __launch_bounds__(256) void k_conv1m(const float* __restrict__ fl,
                                                const float* __restrict__ fu,
                                                const bf16_t* __restrict__ wp1,
                                                float* __restrict__ outp) {
    __shared__ __align__(16) bf16_t X[64][X1LD];
    int t = threadIdx.x, lane = t & 63, w = t >> 6;
    int b = blockIdx.x >> 8;
    int pos0 = (blockIdx.x & 255) << 6;
    f32x4 acc[2][4];
    #pragma unroll
    for (int i = 0; i < 2; ++i)
        #pragma unroll
        for (int j = 0; j < 4; ++j)
            acc[i][j] = (f32x4){0.f, 0.f, 0.f, 0.f};
    // stage: cpair cp = it*4+w (wave-uniform), 64 pos = lanes; coalesced 256B loads
    #pragma unroll 4
    for (int it = 0; it < 32; ++it) {
        int cp = it * 4 + w;
        int c = cp * 2;
        float v0, v1;
        if (c < 128) {
            size_t gb = (size_t)(b * 128 + c) * HWs + pos0 + lane;
            v0 = fl[gb]; v1 = fl[gb + HWs];
        } else {
            size_t gb = (size_t)(b * 128 + (c - 128)) * HWs + pos0 + lane;
            v0 = 2.0f * fu[gb]; v1 = 2.0f * fu[gb + HWs];
        }
        X[lane][c] = (bf16_t)v0;
        X[lane][c + 1] = (bf16_t)v1;
    }
    __syncthreads();
    #pragma unroll
    for (int ks = 0; ks < 8; ++ks) {
        bf16x8 af[2], bfr[4];
        const bf16x8* wp = (const bf16x8*)wp1 + ((ks * 8 + w * 2) * 64 + lane);
        af[0] = wp[0];
        af[1] = wp[64];
        #pragma unroll
        for (int pi = 0; pi < 4; ++pi)
            bfr[pi] = *(const bf16x8*)&X[pi * 16 + (lane & 15)][ks * 32 + ((lane >> 4) << 3)];
        #pragma unroll
        for (int oi = 0; oi < 2; ++oi)
            #pragma unroll
            for (int pi = 0; pi < 4; ++pi)
                acc[oi][pi] = __builtin_amdgcn_mfma_f32_16x16x32_bf16(af[oi], bfr[pi], acc[oi][pi], 0, 0, 0);
    }
    #pragma unroll
    for (int oi = 0; oi < 2; ++oi) {
        int obase = (w * 2 + oi) * 16 + ((lane >> 4) << 2);
        #pragma unroll
        for (int j = 0; j < 4; ++j) {
            int o = obase + j;
            size_t ob = (size_t)(b * 128 + o) * HWs + pos0 + (lane & 15);
            #pragma unroll
            for (int pi = 0; pi < 4; ++pi)
                outp[ob + pi * 16] = acc[oi][pi][j];
        }
    }
}

// ---------------- 3x3 conv via MFMA ----------------
#define X3LD 40
__global__ __launch_bounds__(256) void k_conv3m(const float* __restrict__ A,
                                                const bf16_t* __restrict__ wpack,
                                                const float* __restrict__ bom,
                                                float* __restrict__ om) {
    __shared__ __align__(16) bf16_t Xs[3 * 66 * X3LD];
    int t = threadIdx.x;
    int lane = t & 63, w = t >> 6;
    int b = blockIdx.x >> 8;
    int pos0 = (blockIdx.x & 255) << 6;
    int y = pos0 >> 7, x0 = pos0 & 127;
    f32x4 acc[4][4];
    #pragma unroll
    for (int i = 0; i < 4; ++i)
        #pragma unroll
        for (int j = 0; j < 4; ++j)
            acc[i][j] = (f32x4){0.f, 0.f, 0.f, 0.f};

    for (int cblk = 0; cblk < 4; ++cblk) {
        __syncthreads();
        for (int id = t; id < 3168; id += 256) {
            int col = id % 66;
            int rest = id / 66;
            int dy = rest % 3;
            int cp = rest / 3;
            int gy = y - 1 + dy, gx = x0 - 1 + col;
            float v0 = 0.f, v1 = 0.f;
            if ((unsigned)gy < 128u && (unsigned)gx < 128u) {
                size_t gb = ((size_t)(b * 128 + cblk * 32 + cp * 2) * 128 + gy) * 128 + gx;
                v0 = A[gb];
                v1 = A[gb + HWs];
            }
            int le = (dy * 66 + col) * X3LD + cp * 2;
            Xs[le] = (bf16_t)v0;
            Xs[le + 1] = (bf16_t)v1;
        }
        __syncthreads();
        #pragma unroll
        for (int tap = 0; tap < 9; ++tap) {
            const int ky = tap / 3, kx = tap % 3;
            bf16x8 af[4], bfr[4];
            const bf16x8* wp = (const bf16x8*)wpack + ((size_t)((cblk * 9 + tap) * 16 + w * 4) * 64 + lane);
            #pragma unroll
            for (int oi = 0; oi < 4; ++oi) af[oi] = wp[oi * 64];
            #pragma unroll
            for (int pi = 0; pi < 4; ++pi) {
                int colb = pi * 16 + (lane & 15) + kx;
                bfr[pi] = *(const bf16x8*)&Xs[(ky * 66 + colb) * X3LD + ((lane >> 4) << 3)];
            }
            #pragma unroll
            for (int oi = 0; oi < 4; ++oi)
                #pragma unroll
                for (int pi = 0; pi < 4; ++pi)
                    acc[oi][pi] = __builtin_amdgcn_mfma_f32_16x16x32_bf16(af[oi], bfr[pi], acc[oi][pi], 0, 0, 0);
        }
    }
    #pragma unroll
    for (int oi = 0; oi < 4; ++oi) {
        int obase = (w * 4 + oi) * 16 + ((lane >> 4) << 2);
        #pragma unroll
        for (int j = 0; j < 4; ++j) {
            int o = obase + j;
            if (o < OMCH) {
                float bv = bom[o];
                size_t ob = (size_t)(b * OMCH + o) * HWs + pos0 + (lane & 15);
                #pragma unroll
                for (int pi = 0; pi < 4; ++pi) {
                    float v = acc[oi][pi][j] + bv;
                    if (o >= 144) v = 1.0f / (1.0f + expf(-v));
                    om[ob + pi * 16] = v;
                }
            }
        }
    }
}

// ---------------- DCNv2 via MFMA + relu + residual ----------------
// 512 threads = 8 waves. 2 groups per barrier interval: 18 (group,tap) units
// over 8 waves (waves 0,1 do 3; others 2). Gather: bilinear params in regs,
// all 64 corner loads issued before consumption (register arrays), 2x b128
// LDS write. MFMA: wave w -> o-tile w, 4 p-tiles, 2 groups x 5 K-steps.
__global__ __launch_bounds__(512, 6) void k_dcn(const float* __restrict__ fu,
                                                const float* __restrict__ om,
                                                const bf16_t* __restrict__ wpd,
                                                const float* __restrict__ bdcn,
                                                const float* __restrict__ fl,
                                                float* __restrict__ outp) {
    __shared__ __align__(16) bf16_t val[2][64][168];
    int t = threadIdx.x;
    int lane = t & 63, w = t >> 6;           // wave 0..7
    int b = blockIdx.x >> 8;
    int pos0 = (blockIdx.x & 255) << 6;
    int y = pos0 >> 7, x0 = pos0 & 127;
    f32x4 acc[4];
    #pragma unroll
    for (int j = 0; j < 4; ++j) acc[j] = (f32x4){0.f, 0.f, 0.f, 0.f};
    // zero the K-pad columns of both buffers once
    for (int id = t; id < 2 * 64 * 24; id += 512) {
        int bufg = id / 1536, r = id % 1536;
        val[bufg][r / 24][144 + (r % 24)] = (bf16_t)0.0f;
    }

    const float* omb = om + (size_t)b * OMCH * HWs;
    for (int gc = 0; gc < 4; ++gc) {
        for (int u = w; u < 18; u += 8) {
            int gl = u / 9;
            int tap = u % 9;
            int g = gc * 2 + gl;
            int ky = tap / 3, kx = tap % 3;
            int x = x0 + lane;
            size_t sp = (size_t)y * 128 + x;
            float oy = omb[(size_t)(g * 18 + tap * 2) * HWs + sp];
            float ox = omb[(size_t)(g * 18 + tap * 2 + 1) * HWs + sp];
            float m  = omb[(size_t)(144 + g * 9 + tap) * HWs + sp];
            float py = (float)(y - 1 + ky) + oy;
            float px = (float)(x - 1 + kx) + ox;
            float fy0 = floorf(py), fx0 = floorf(px);
            float ly = py - fy0, lx = px - fx0;
            int y0 = (int)fy0, x0i = (int)fx0;
            int y1 = y0 + 1, x1 = x0i + 1;
            float vy0 = ((unsigned)y0 < 128u) ? 1.0f : 0.0f;
            float vy1 = ((unsigned)y1 < 128u) ? 1.0f : 0.0f;
            float vx0 = ((unsigned)x0i < 128u) ? 1.0f : 0.0f;
            float vx1 = ((unsigned)x1 < 128u) ? 1.0f : 0.0f;
            int yc0 = min(max(y0, 0), 127), yc1 = min(max(y1, 0), 127);
            int xc0 = min(max(x0i, 0), 127), xc1 = min(max(x1, 0), 127);
            float pw00 = (1.0f - ly) * (1.0f - lx) * m * vy0 * vx0;
            float pw01 = (1.0f - ly) * lx * m * vy0 * vx1;
            float pw10 = ly * (1.0f - lx) * m * vy1 * vx0;
            float pw11 = ly * lx * m * vy1 * vx1;
            int a00 = yc0 * 128 + xc0, a01 = yc0 * 128 + xc1;
            int a10 = yc1 * 128 + xc0, a11 = yc1 * 128 + xc1;
            const float* bp = fu + (size_t)(b * 128 + g * 16) * HWs;
            // issue all 64 corner loads before consuming (MLP)
            float v00[16], v01[16], v10[16], v11[16];
            #pragma unroll
            for (int c = 0; c < 16; ++c) {
                const float* p = bp + (size_t)c * HWs;
                v00[c] = p[a00]; v01[c] = p[a01]; v10[c] = p[a10]; v11[c] = p[a11];
            }
            bf16x8 lo, hi;
            #pragma unroll
            for (int c = 0; c < 16; ++c) {
                float v = pw00 * v00[c] + pw01 * v01[c] + pw10 * v10[c] + pw11 * v11[c];
                if (c < 8) lo[c] = (bf16_t)v; else hi[c - 8] = (bf16_t)v;
            }
            *(bf16x8*)&val[gl][lane][tap * 16] = lo;
            *(bf16x8*)&val[gl][lane][tap * 16 + 8] = hi;
        }
        __syncthreads();
        #pragma unroll
        for (int gl = 0; gl < 2; ++gl) {
            int g = gc * 2 + gl;
            #pragma unroll
            for (int ks = 0; ks < 5; ++ks) {
                bf16x8 af = *((const bf16x8*)wpd + (((g * 5 + ks) * 8 + w) * 64 + lane));
                #pragma unroll
                for (int pi = 0; pi < 4; ++pi) {
                    bf16x8 bfr = *(const bf16x8*)&val[gl][pi * 16 + (lane & 15)][ks * 32 + ((lane >> 4) << 3)];
                    acc[pi] = __builtin_amdgcn_mfma_f32_16x16x32_bf16(af, bfr, acc[pi], 0, 0, 0);
                }
            }
        }
        __syncthreads();
    }
    // epilogue: +bias, relu, +feat_l
    #pragma unroll
    for (int j = 0; j < 4; ++j) {
        int o = w * 16 + ((lane >> 4) << 2) + j;
        float bv = bdcn[o];
        size_t base = (size_t)(b * 128 + o) * HWs + pos0 + (lane & 15);
        #pragma unroll
        for (int pi = 0; pi < 4; ++pi) {
            float v = fmaxf(acc[pi][j] + bv, 0.0f) + fl[base + pi * 16];
            outp[base + pi * 16] = v;
        }
    }
}

extern "C" void kernel_launch(void* const* d_in, const int* in_sizes, int n_in,
                              void* d_out, int out_size, void* d_ws, size_t ws_size,
                              hipStream_t stream) {
    const float* feat_l = (const float*)d_in[0];
    const float* feat_s = (const float*)d_in[1];
    const float* W_off  = (const float*)d_in[2];
    const float* W_om   = (const float*)d_in[3];
    const float* b_om   = (const float*)d_in[4];
    const float* W_dcn  = (const float*)d_in[5];
    const float* b_dcn  = (const float*)d_in[6];
    float* out = (float*)d_out;
    float* ws = (float*)d_ws;

    float* feat_up = ws;                        // 8,388,608 f
    float* offs    = ws + 8388608;              // 8,388,608 f
    float* om      = ws + 16777216;             // 14,155,776 f
    bf16_t* wpack1 = (bf16_t*)(ws + 30932992);  // 32,768 bf16 = 16,384 f
    bf16_t* wpack  = (bf16_t*)(ws + 30949376);  // 294,912 bf16 = 147,456 f
    bf16_t* wpdcn  = (bf16_t*)(ws + 31096832);  // 163,840 bf16 = 81,920 f

    k_prep<<<240, 256, 0, stream>>>(W_off, W_om, W_dcn, wpack1, wpack, wpdcn);
    k_upsample<<<32768, 256, 0, stream>>>(feat_s, feat_up);
    k_conv1m<<<1024, 256, 0, stream>>>(feat_l, feat_up, wpack1, offs);
    k_conv3m<<<1024, 256, 0, stream>>>(offs, wpack, b_om, om);
    k_dcn<<<1024, 512, 0, stream>>>(feat_up, om, wpdcn, b_dcn, feat_l, out);
}

// Round 6
// 402.617 us; speedup vs baseline: 1.2131x; 1.2131x over previous
//
#include <hip/hip_runtime.h>
#include <hip/hip_bf16.h>
#include <math.h>

#define BB 4
#define CC 128
#define HH 128
#define WW 128
#define HWs 16384
#define GG 8
#define OMCH 216

typedef __bf16 bf16_t;
typedef bf16_t bf16x8 __attribute__((ext_vector_type(8)));
typedef float f32x4 __attribute__((ext_vector_type(4)));
typedef float f32x2 __attribute__((ext_vector_type(2), aligned(4)));

// ---------------- prep: weight rearrange ----------------
__global__ __launch_bounds__(256) void k_prep(const float* __restrict__ W_off,
                                              const float* __restrict__ W_om,
                                              const float* __restrict__ W_dcn,
                                              bf16_t* __restrict__ wpack1,
                                              bf16_t* __restrict__ wpack,
                                              bf16_t* __restrict__ wpdcn) {
    int idx = blockIdx.x * 256 + threadIdx.x;
    if (idx < 4096) {
        int j = idx;
        int lane = j & 63;
        int rest = j >> 6;       // 0..63
        int ot = rest & 7;
        int ks = rest >> 3;      // 0..7
        int o = ot * 16 + (lane & 15);
        int cbase = ks * 32 + ((lane >> 4) << 3);
        bf16x8 v;
        #pragma unroll
        for (int r = 0; r < 8; ++r) v[r] = (bf16_t)W_off[o * 256 + cbase + r];
        *((bf16x8*)wpack1 + j) = v;
    } else if (idx < 4096 + 36864) {
        int j = idx - 4096;
        int lane = j & 63;
        int rest = j >> 6;       // 0..575
        int ot = rest & 15;
        int ks = rest >> 4;      // 0..35
        int cblk = ks / 9, tap = ks % 9;
        int o = ot * 16 + (lane & 15);
        int cbase = cblk * 32 + ((lane >> 4) << 3);
        bf16x8 v;
        #pragma unroll
        for (int r = 0; r < 8; ++r) {
            float x = (o < OMCH) ? W_om[((o * 128 + cbase + r) * 9) + tap] : 0.0f;
            v[r] = (bf16_t)x;
        }
        *((bf16x8*)wpack + j) = v;
    } else if (idx < 4096 + 36864 + 20480) {
        int j = idx - 40960;
        int lane = j & 63;
        int rest = j >> 6;       // 0..319
        int ot = rest & 7;
        int gks = rest >> 3;     // 0..39
        int g = gks / 5, ks = gks % 5;
        int o = ot * 16 + (lane & 15);
        int Kbase = ks * 32 + ((lane >> 4) << 3);
        bf16x8 v;
        #pragma unroll
        for (int r = 0; r < 8; ++r) {
            int K = Kbase + r;
            float x = 0.0f;
            if (K < 144) {
                int tap = K >> 4, cpp = K & 15;
                x = W_dcn[((o * 128) + g * 16 + cpp) * 9 + tap];
            }
            v[r] = (bf16_t)x;
        }
        *((bf16x8*)wpdcn + j) = v;
    }
}

// ---------------- bilinear 2x upsample ----------------
__global__ __launch_bounds__(256) void k_upsample(const float* __restrict__ fs,
                                                  float* __restrict__ fu) {
    int idx = blockIdx.x * 256 + threadIdx.x;
    int x = idx & 127, y = (idx >> 7) & 127, bc = idx >> 14;
    int j = y >> 1, i = x >> 1;
    int ya, yb; float wya, wyb;
    if (y & 1) { ya = j; yb = (j < 63) ? j + 1 : 63; wya = 0.75f; wyb = 0.25f; }
    else       { ya = (j > 0) ? j - 1 : 0; yb = j;   wya = 0.25f; wyb = 0.75f; }
    int xa, xb; float wxa, wxb;
    if (x & 1) { xa = i; xb = (i < 63) ? i + 1 : 63; wxa = 0.75f; wxb = 0.25f; }
    else       { xa = (i > 0) ? i - 1 : 0; xb = i;   wxa = 0.25f; wxb = 0.75f; }
    const float* p = fs + (size_t)bc * 4096;
    float v = wya * (wxa * p[ya * 64 + xa] + wxb * p[ya * 64 + xb])
            + wyb * (wxa * p[yb * 64 + xa] + wxb * p[yb * 64 + xb]);
    fu[idx] = v;
}

// ---------------- 1x1 conv via MFMA ----------------
#define X1LD 264
__global__ __launch_bounds__(256) void k_conv1m(const float* __restrict__ fl,
                                                const float* __restrict__ fu,
                                                const bf16_t* __restrict__ wp1,
                                                float* __restrict__ outp) {
    __shared__ __align__(16) bf16_t X[64][X1LD];
    int t = threadIdx.x, lane = t & 63, w = t >> 6;
    int b = blockIdx.x >> 8;
    int pos0 = (blockIdx.x & 255) << 6;
    f32x4 acc[2][4];
    #pragma unroll
    for (int i = 0; i < 2; ++i)
        #pragma unroll
        for (int j = 0; j < 4; ++j)
            acc[i][j] = (f32x4){0.f, 0.f, 0.f, 0.f};
    #pragma unroll 4
    for (int it = 0; it < 32; ++it) {
        int cp = it * 4 + w;
        int c = cp * 2;
        float v0, v1;
        if (c < 128) {
            size_t gb = (size_t)(b * 128 + c) * HWs + pos0 + lane;
            v0 = fl[gb]; v1 = fl[gb + HWs];
        } else {
            size_t gb = (size_t)(b * 128 + (c - 128)) * HWs + pos0 + lane;
            v0 = 2.0f * fu[gb]; v1 = 2.0f * fu[gb + HWs];
        }
        X[lane][c] = (bf16_t)v0;
        X[lane][c + 1] = (bf16_t)v1;
    }
    __syncthreads();
    #pragma unroll
    for (int ks = 0; ks < 8; ++ks) {
        bf16x8 af[2], bfr[4];
        const bf16x8* wp = (const bf16x8*)wp1 + ((ks * 8 + w * 2) * 64 + lane);
        af[0] = wp[0];
        af[1] = wp[64];
        #pragma unroll
        for (int pi = 0; pi < 4; ++pi)
            bfr[pi] = *(const bf16x8*)&X[pi * 16 + (lane & 15)][ks * 32 + ((lane >> 4) << 3)];
        #pragma unroll
        for (int oi = 0; oi < 2; ++oi)
            #pragma unroll
            for (int pi = 0; pi < 4; ++pi)
                acc[oi][pi] = __builtin_amdgcn_mfma_f32_16x16x32_bf16(af[oi], bfr[pi], acc[oi][pi], 0, 0, 0);
    }
    #pragma unroll
    for (int oi = 0; oi < 2; ++oi) {
        int obase = (w * 2 + oi) * 16 + ((lane >> 4) << 2);
        #pragma unroll
        for (int j = 0; j < 4; ++j) {
            int o = obase + j;
            size_t ob = (size_t)(b * 128 + o) * HWs + pos0 + (lane & 15);
            #pragma unroll
            for (int pi = 0; pi < 4; ++pi)
                outp[ob + pi * 16] = acc[oi][pi][j];
        }
    }
}

// ---------------- 3x3 conv via MFMA ----------------
#define X3LD 40
__global__ __launch_bounds__(256) void k_conv3m(const float* __restrict__ A,
                                                const bf16_t* __restrict__ wpack,
                                                const float* __restrict__ bom,
                                                float* __restrict__ om) {
    __shared__ __align__(16) bf16_t Xs[3 * 66 * X3LD];
    int t = threadIdx.x;
    int lane = t & 63, w = t >> 6;
    int b = blockIdx.x >> 8;
    int pos0 = (blockIdx.x & 255) << 6;
    int y = pos0 >> 7, x0 = pos0 & 127;
    f32x4 acc[4][4];
    #pragma unroll
    for (int i = 0; i < 4; ++i)
        #pragma unroll
        for (int j = 0; j < 4; ++j)
            acc[i][j] = (f32x4){0.f, 0.f, 0.f, 0.f};

    for (int cblk = 0; cblk < 4; ++cblk) {
        __syncthreads();
        for (int id = t; id < 3168; id += 256) {
            int col = id % 66;
            int rest = id / 66;
            int dy = rest % 3;
            int cp = rest / 3;
            int gy = y - 1 + dy, gx = x0 - 1 + col;
            float v0 = 0.f, v1 = 0.f;
            if ((unsigned)gy < 128u && (unsigned)gx < 128u) {
                size_t gb = ((size_t)(b * 128 + cblk * 32 + cp * 2) * 128 + gy) * 128 + gx;
                v0 = A[gb];
                v1 = A[gb + HWs];
            }
            int le = (dy * 66 + col) * X3LD + cp * 2;
            Xs[le] = (bf16_t)v0;
            Xs[le + 1] = (bf16_t)v1;
        }
        __syncthreads();
        #pragma unroll
        for (int tap = 0; tap < 9; ++tap) {
            const int ky = tap / 3, kx = tap % 3;
            bf16x8 af[4], bfr[4];
            const bf16x8* wp = (const bf16x8*)wpack + ((size_t)((cblk * 9 + tap) * 16 + w * 4) * 64 + lane);
            #pragma unroll
            for (int oi = 0; oi < 4; ++oi) af[oi] = wp[oi * 64];
            #pragma unroll
            for (int pi = 0; pi < 4; ++pi) {
                int colb = pi * 16 + (lane & 15) + kx;
                bfr[pi] = *(const bf16x8*)&Xs[(ky * 66 + colb) * X3LD + ((lane >> 4) << 3)];
            }
            #pragma unroll
            for (int oi = 0; oi < 4; ++oi)
                #pragma unroll
                for (int pi = 0; pi < 4; ++pi)
                    acc[oi][pi] = __builtin_amdgcn_mfma_f32_16x16x32_bf16(af[oi], bfr[pi], acc[oi][pi], 0, 0, 0);
        }
    }
    #pragma unroll
    for (int oi = 0; oi < 4; ++oi) {
        int obase = (w * 4 + oi) * 16 + ((lane >> 4) << 2);
        #pragma unroll
        for (int j = 0; j < 4; ++j) {
            int o = obase + j;
            if (o < OMCH) {
                float bv = bom[o];
                size_t ob = (size_t)(b * OMCH + o) * HWs + pos0 + (lane & 15);
                #pragma unroll
                for (int pi = 0; pi < 4; ++pi) {
                    float v = acc[oi][pi][j] + bv;
                    if (o >= 144) v = 1.0f / (1.0f + expf(-v));
                    om[ob + pi * 16] = v;
                }
            }
        }
    }
}

// ---------------- DCNv2 via MFMA + relu + residual ----------------
// 512 threads = 8 waves, 2 groups per barrier interval (18 units over 8 waves).
// Gather: bilinear params in regs; x-pair corners fetched as ONE float2 per
// (channel,row) with per-unit select-folded weights; 8-channel batches in
// small register arrays (no spill under the 85-VGPR cap).
__global__ __launch_bounds__(512, 6) void k_dcn(const float* __restrict__ fu,
                                                const float* __restrict__ om,
                                                const bf16_t* __restrict__ wpd,
                                                const float* __restrict__ bdcn,
                                                const float* __restrict__ fl,
                                                float* __restrict__ outp) {
    __shared__ __align__(16) bf16_t val[2][64][168];
    int t = threadIdx.x;
    int lane = t & 63, w = t >> 6;           // wave 0..7
    int b = blockIdx.x >> 8;
    int pos0 = (blockIdx.x & 255) << 6;
    int y = pos0 >> 7, x0 = pos0 & 127;
    f32x4 acc[4];
    #pragma unroll
    for (int j = 0; j < 4; ++j) acc[j] = (f32x4){0.f, 0.f, 0.f, 0.f};
    for (int id = t; id < 2 * 64 * 24; id += 512) {
        int bufg = id / 1536, r = id % 1536;
        val[bufg][r / 24][144 + (r % 24)] = (bf16_t)0.0f;
    }

    const float* omb = om + (size_t)b * OMCH * HWs;
    const float* fub = fu + (size_t)b * 128 * HWs;

    auto gather_unit = [&](int gc, int u) __attribute__((always_inline)) {
        int gl = u / 9;
        int tap = u % 9;
        int g = gc * 2 + gl;
        int ky = tap / 3, kx = tap % 3;
        int x = x0 + lane;
        size_t sp = (size_t)y * 128 + x;
        float oy = omb[(size_t)(g * 18 + tap * 2) * HWs + sp];
        float ox = omb[(size_t)(g * 18 + tap * 2 + 1) * HWs + sp];
        float m  = omb[(size_t)(144 + g * 9 + tap) * HWs + sp];
        float py = (float)(y - 1 + ky) + oy;
        float px = (float)(x - 1 + kx) + ox;
        float fy0 = floorf(py), fx0 = floorf(px);
        float ly = py - fy0, lx = px - fx0;
        int y0 = (int)fy0, x0i = (int)fx0;
        float vy0 = ((unsigned)y0 < 128u) ? 1.0f : 0.0f;
        float vy1 = ((unsigned)(y0 + 1) < 128u) ? 1.0f : 0.0f;
        float vx0 = ((unsigned)x0i < 128u) ? 1.0f : 0.0f;
        float vx1 = ((unsigned)(x0i + 1) < 128u) ? 1.0f : 0.0f;
        int yc0 = min(max(y0, 0), 127), yc1 = min(max(y0 + 1, 0), 127);
        int xc0 = min(max(x0i, 0), 127), xc1 = min(max(x0i + 1, 0), 127);
        float pw00 = (1.0f - ly) * (1.0f - lx) * m * vy0 * vx0;
        float pw01 = (1.0f - ly) * lx * m * vy0 * vx1;
        float pw10 = ly * (1.0f - lx) * m * vy1 * vx0;
        float pw11 = ly * lx * m * vy1 * vx1;
        int xr = min(xc0, 126);
        int s0 = xc0 - xr;            // 0/1
        int s1 = xc1 - xr;            // 0/1
        // fold the x-select into per-unit weights (uniform over channels)
        float ax = (s0 ? 0.0f : pw00) + (s1 ? 0.0f : pw01);
        float ay = (s0 ? pw00 : 0.0f) + (s1 ? pw01 : 0.0f);
        float bx = (s0 ? 0.0f : pw10) + (s1 ? 0.0f : pw11);
        float by = (s0 ? pw10 : 0.0f) + (s1 ? pw11 : 0.0f);
        int a_lo = yc0 * 128 + xr;
        int a_hi = yc1 * 128 + xr;
        const float* bp = fub + (size_t)(g * 16) * HWs;
        #pragma unroll
        for (int half = 0; half < 2; ++half) {
            f32x2 ra[8], rb[8];
            #pragma unroll
            for (int c = 0; c < 8; ++c) {
                const float* p = bp + (size_t)(half * 8 + c) * HWs;
                ra[c] = *(const f32x2*)(p + a_lo);
                rb[c] = *(const f32x2*)(p + a_hi);
            }
            bf16x8 ov;
            #pragma unroll
            for (int c = 0; c < 8; ++c) {
                float v = ax * ra[c][0] + ay * ra[c][1] + bx * rb[c][0] + by * rb[c][1];
                ov[c] = (bf16_t)v;
            }
            *(bf16x8*)&val[gl][lane][tap * 16 + half * 8] = ov;
        }
    };

    for (int gc = 0; gc < 4; ++gc) {
        gather_unit(gc, w);
        gather_unit(gc, w + 8);
        if (w < 2) gather_unit(gc, w + 16);
        __syncthreads();
        #pragma unroll
        for (int gl = 0; gl < 2; ++gl) {
            int g = gc * 2 + gl;
            #pragma unroll
            for (int ks = 0; ks < 5; ++ks) {
                bf16x8 af = *((const bf16x8*)wpd + (((g * 5 + ks) * 8 + w) * 64 + lane));
                #pragma unroll
                for (int pi = 0; pi < 4; ++pi) {
                    bf16x8 bfr = *(const bf16x8*)&val[gl][pi * 16 + (lane & 15)][ks * 32 + ((lane >> 4) << 3)];
                    acc[pi] = __builtin_amdgcn_mfma_f32_16x16x32_bf16(af, bfr, acc[pi], 0, 0, 0);
                }
            }
        }
        __syncthreads();
    }
    #pragma unroll
    for (int j = 0; j < 4; ++j) {
        int o = w * 16 + ((lane >> 4) << 2) + j;
        float bv = bdcn[o];
        size_t base = (size_t)(b * 128 + o) * HWs + pos0 + (lane & 15);
        #pragma unroll
        for (int pi = 0; pi < 4; ++pi) {
            float v = fmaxf(acc[pi][j] + bv, 0.0f) + fl[base + pi * 16];
            outp[base + pi * 16] = v;
        }
    }
}

extern "C" void kernel_launch(void* const* d_in, const int* in_sizes, int n_in,
                              void* d_out, int out_size, void* d_ws, size_t ws_size,
                              hipStream_t stream) {
    const float* feat_l = (const float*)d_in[0];
    const float* feat_s = (const float*)d_in[1];
    const float* W_off  = (const float*)d_in[2];
    const float* W_om   = (const float*)d_in[3];
    const float* b_om   = (const float*)d_in[4];
    const float* W_dcn  = (const float*)d_in[5];
    const float* b_dcn  = (const float*)d_in[6];
    float* out = (float*)d_out;
    float* ws = (float*)d_ws;

    float* feat_up = ws;                        // 8,388,608 f
    float* offs    = ws + 8388608;              // 8,388,608 f
    float* om      = ws + 16777216;             // 14,155,776 f
    bf16_t* wpack1 = (bf16_t*)(ws + 30932992);  // 32,768 bf16
    bf16_t* wpack  = (bf16_t*)(ws + 30949376);  // 294,912 bf16
    bf16_t* wpdcn  = (bf16_t*)(ws + 31096832);  // 163,840 bf16

    k_prep<<<240, 256, 0, stream>>>(W_off, W_om, W_dcn, wpack1, wpack, wpdcn);
    k_upsample<<<32768, 256, 0, stream>>>(feat_s, feat_up);
    k_conv1m<<<1024, 256, 0, stream>>>(feat_l, feat_up, wpack1, offs);
    k_conv3m<<<1024, 256, 0, stream>>>(offs, wpack, b_om, om);
    k_dcn<<<1024, 512, 0, stream>>>(feat_up, om, wpdcn, b_dcn, feat_l, out);
}

// Round 8
// 400.951 us; speedup vs baseline: 1.2181x; 1.0042x over previous
//
#include <hip/hip_runtime.h>
#include <hip/hip_bf16.h>
#include <math.h>

#define BB 4
#define CC 128
#define HH 128
#define WW 128
#define HWs 16384
#define GG 8
#define OMCH 216

typedef __bf16 bf16_t;
typedef bf16_t bf16x8 __attribute__((ext_vector_type(8)));
typedef float f32x4 __attribute__((ext_vector_type(4)));
typedef float f32x2 __attribute__((ext_vector_type(2), aligned(4)));

// ---------------- prep: weight rearrange ----------------
__global__ __launch_bounds__(256) void k_prep(const float* __restrict__ W_off,
                                              const float* __restrict__ W_om,
                                              const float* __restrict__ W_dcn,
                                              bf16_t* __restrict__ wpack1,
                                              bf16_t* __restrict__ wpack,
                                              bf16_t* __restrict__ wpdcn) {
    int idx = blockIdx.x * 256 + threadIdx.x;
    if (idx < 4096) {
        int j = idx;
        int lane = j & 63;
        int rest = j >> 6;       // 0..63
        int ot = rest & 7;
        int ks = rest >> 3;      // 0..7
        int o = ot * 16 + (lane & 15);
        int cbase = ks * 32 + ((lane >> 4) << 3);
        bf16x8 v;
        #pragma unroll
        for (int r = 0; r < 8; ++r) v[r] = (bf16_t)W_off[o * 256 + cbase + r];
        *((bf16x8*)wpack1 + j) = v;
    } else if (idx < 4096 + 36864) {
        int j = idx - 4096;
        int lane = j & 63;
        int rest = j >> 6;       // 0..575
        int ot = rest & 15;
        int ks = rest >> 4;      // 0..35
        int cblk = ks / 9, tap = ks % 9;
        int o = ot * 16 + (lane & 15);
        int cbase = cblk * 32 + ((lane >> 4) << 3);
        bf16x8 v;
        #pragma unroll
        for (int r = 0; r < 8; ++r) {
            float x = (o < OMCH) ? W_om[((o * 128 + cbase + r) * 9) + tap] : 0.0f;
            v[r] = (bf16_t)x;
        }
        *((bf16x8*)wpack + j) = v;
    } else if (idx < 4096 + 36864 + 20480) {
        int j = idx - 40960;
        int lane = j & 63;
        int rest = j >> 6;       // 0..319
        int ot = rest & 7;
        int gks = rest >> 3;     // 0..39
        int g = gks / 5, ks = gks % 5;
        int o = ot * 16 + (lane & 15);
        int Kbase = ks * 32 + ((lane >> 4) << 3);
        bf16x8 v;
        #pragma unroll
        for (int r = 0; r < 8; ++r) {
            int K = Kbase + r;
            float x = 0.0f;
            if (K < 144) {
                int tap = K >> 4, cpp = K & 15;
                x = W_dcn[((o * 128) + g * 16 + cpp) * 9 + tap];
            }
            v[r] = (bf16_t)x;
        }
        *((bf16x8*)wpdcn + j) = v;
    }
}

// ---------------- bilinear 2x upsample ----------------
__global__ __launch_bounds__(256) void k_upsample(const float* __restrict__ fs,
                                                  float* __restrict__ fu) {
    int idx = blockIdx.x * 256 + threadIdx.x;
    int x = idx & 127, y = (idx >> 7) & 127, bc = idx >> 14;
    int j = y >> 1, i = x >> 1;
    int ya, yb; float wya, wyb;
    if (y & 1) { ya = j; yb = (j < 63) ? j + 1 : 63; wya = 0.75f; wyb = 0.25f; }
    else       { ya = (j > 0) ? j - 1 : 0; yb = j;   wya = 0.25f; wyb = 0.75f; }
    int xa, xb; float wxa, wxb;
    if (x & 1) { xa = i; xb = (i < 63) ? i + 1 : 63; wxa = 0.75f; wxb = 0.25f; }
    else       { xa = (i > 0) ? i - 1 : 0; xb = i;   wxa = 0.25f; wxb = 0.75f; }
    const float* p = fs + (size_t)bc * 4096;
    float v = wya * (wxa * p[ya * 64 + xa] + wxb * p[ya * 64 + xb])
            + wyb * (wxa * p[yb * 64 + xa] + wxb * p[yb * 64 + xb]);
    fu[idx] = v;
}

// ---------------- 1x1 conv via MFMA ----------------
#define X1LD 264
__global__ __launch_bounds__(256) void k_conv1m(const float* __restrict__ fl,
                                                const float* __restrict__ fu,
                                                const bf16_t* __restrict__ wp1,
                                                float* __restrict__ outp) {
    __shared__ __align__(16) bf16_t X[64][X1LD];
    int t = threadIdx.x, lane = t & 63, w = t >> 6;
    int b = blockIdx.x >> 8;
    int pos0 = (blockIdx.x & 255) << 6;
    f32x4 acc[2][4];
    #pragma unroll
    for (int i = 0; i < 2; ++i)
        #pragma unroll
        for (int j = 0; j < 4; ++j)
            acc[i][j] = (f32x4){0.f, 0.f, 0.f, 0.f};
    #pragma unroll 4
    for (int it = 0; it < 32; ++it) {
        int cp = it * 4 + w;
        int c = cp * 2;
        float v0, v1;
        if (c < 128) {
            size_t gb = (size_t)(b * 128 + c) * HWs + pos0 + lane;
            v0 = fl[gb]; v1 = fl[gb + HWs];
        } else {
            size_t gb = (size_t)(b * 128 + (c - 128)) * HWs + pos0 + lane;
            v0 = 2.0f * fu[gb]; v1 = 2.0f * fu[gb + HWs];
        }
        X[lane][c] = (bf16_t)v0;
        X[lane][c + 1] = (bf16_t)v1;
    }
    __syncthreads();
    #pragma unroll
    for (int ks = 0; ks < 8; ++ks) {
        bf16x8 af[2], bfr[4];
        const bf16x8* wp = (const bf16x8*)wp1 + ((ks * 8 + w * 2) * 64 + lane);
        af[0] = wp[0];
        af[1] = wp[64];
        #pragma unroll
        for (int pi = 0; pi < 4; ++pi)
            bfr[pi] = *(const bf16x8*)&X[pi * 16 + (lane & 15)][ks * 32 + ((lane >> 4) << 3)];
        #pragma unroll
        for (int oi = 0; oi < 2; ++oi)
            #pragma unroll
            for (int pi = 0; pi < 4; ++pi)
                acc[oi][pi] = __builtin_amdgcn_mfma_f32_16x16x32_bf16(af[oi], bfr[pi], acc[oi][pi], 0, 0, 0);
    }
    #pragma unroll
    for (int oi = 0; oi < 2; ++oi) {
        int obase = (w * 2 + oi) * 16 + ((lane >> 4) << 2);
        #pragma unroll
        for (int j = 0; j < 4; ++j) {
            int o = obase + j;
            size_t ob = (size_t)(b * 128 + o) * HWs + pos0 + (lane & 15);
            #pragma unroll
            for (int pi = 0; pi < 4; ++pi)
                outp[ob + pi * 16] = acc[oi][pi][j];
        }
    }
}

// ---------------- 3x3 conv via MFMA ----------------
#define X3LD 40
__global__ __launch_bounds__(256) void k_conv3m(const float* __restrict__ A,
                                                const bf16_t* __restrict__ wpack,
                                                const float* __restrict__ bom,
                                                float* __restrict__ om) {
    __shared__ __align__(16) bf16_t Xs[3 * 66 * X3LD];
    int t = threadIdx.x;
    int lane = t & 63, w = t >> 6;
    int b = blockIdx.x >> 8;
    int pos0 = (blockIdx.x & 255) << 6;
    int y = pos0 >> 7, x0 = pos0 & 127;
    f32x4 acc[4][4];
    #pragma unroll
    for (int i = 0; i < 4; ++i)
        #pragma unroll
        for (int j = 0; j < 4; ++j)
            acc[i][j] = (f32x4){0.f, 0.f, 0.f, 0.f};

    for (int cblk = 0; cblk < 4; ++cblk) {
        __syncthreads();
        for (int id = t; id < 3168; id += 256) {
            int col = id % 66;
            int rest = id / 66;
            int dy = rest % 3;
            int cp = rest / 3;
            int gy = y - 1 + dy, gx = x0 - 1 + col;
            float v0 = 0.f, v1 = 0.f;
            if ((unsigned)gy < 128u && (unsigned)gx < 128u) {
                size_t gb = ((size_t)(b * 128 + cblk * 32 + cp * 2) * 128 + gy) * 128 + gx;
                v0 = A[gb];
                v1 = A[gb + HWs];
            }
            int le = (dy * 66 + col) * X3LD + cp * 2;
            Xs[le] = (bf16_t)v0;
            Xs[le + 1] = (bf16_t)v1;
        }
        __syncthreads();
        #pragma unroll
        for (int tap = 0; tap < 9; ++tap) {
            const int ky = tap / 3, kx = tap % 3;
            bf16x8 af[4], bfr[4];
            const bf16x8* wp = (const bf16x8*)wpack + ((size_t)((cblk * 9 + tap) * 16 + w * 4) * 64 + lane);
            #pragma unroll
            for (int oi = 0; oi < 4; ++oi) af[oi] = wp[oi * 64];
            #pragma unroll
            for (int pi = 0; pi < 4; ++pi) {
                int colb = pi * 16 + (lane & 15) + kx;
                bfr[pi] = *(const bf16x8*)&Xs[(ky * 66 + colb) * X3LD + ((lane >> 4) << 3)];
            }
            #pragma unroll
            for (int oi = 0; oi < 4; ++oi)
                #pragma unroll
                for (int pi = 0; pi < 4; ++pi)
                    acc[oi][pi] = __builtin_amdgcn_mfma_f32_16x16x32_bf16(af[oi], bfr[pi], acc[oi][pi], 0, 0, 0);
        }
    }
    #pragma unroll
    for (int oi = 0; oi < 4; ++oi) {
        int obase = (w * 4 + oi) * 16 + ((lane >> 4) << 2);
        #pragma unroll
        for (int j = 0; j < 4; ++j) {
            int o = obase + j;
            if (o < OMCH) {
                float bv = bom[o];
                size_t ob = (size_t)(b * OMCH + o) * HWs + pos0 + (lane & 15);
                #pragma unroll
                for (int pi = 0; pi < 4; ++pi) {
                    float v = acc[oi][pi][j] + bv;
                    if (o >= 144) v = 1.0f / (1.0f + expf(-v));
                    om[ob + pi * 16] = v;
                }
            }
        }
    }
}

// ---------------- DCNv2 via MFMA + relu + residual ----------------
// 512 threads = 8 waves, 2 groups per barrier interval (18 units over 8 waves).
// om params for ALL of this wave's units are loaded up-front (one latency),
// then units processed with 4-channel corner batches (16 VGPRs live -> no
// spill under the 85-VGPR cap of __launch_bounds__(512,6)).
__global__ __launch_bounds__(512, 6) void k_dcn(const float* __restrict__ fu,
                                                const float* __restrict__ om,
                                                const bf16_t* __restrict__ wpd,
                                                const float* __restrict__ bdcn,
                                                const float* __restrict__ fl,
                                                float* __restrict__ outp) {
    __shared__ __align__(16) bf16_t val[2][64][168];
    int t = threadIdx.x;
    int lane = t & 63, w = t >> 6;           // wave 0..7
    int b = blockIdx.x >> 8;
    int pos0 = (blockIdx.x & 255) << 6;
    int y = pos0 >> 7, x0 = pos0 & 127;
    f32x4 acc[4];
    #pragma unroll
    for (int j = 0; j < 4; ++j) acc[j] = (f32x4){0.f, 0.f, 0.f, 0.f};
    for (int id = t; id < 2 * 64 * 24; id += 512) {
        int bufg = id / 1536, r = id % 1536;
        val[bufg][r / 24][144 + (r % 24)] = (bf16_t)0.0f;
    }

    const float* omb = om + (size_t)b * OMCH * HWs;
    const float* fub = fu + (size_t)b * 128 * HWs;
    size_t sp = (size_t)y * 128 + x0 + lane;

    // process one gather unit given its pre-loaded params
    auto process_unit = [&](int gl, int g, int tap, float oy, float ox, float m)
        __attribute__((always_inline)) {
        int ky = tap / 3, kx = tap % 3;
        int x = x0 + lane;
        float py = (float)(y - 1 + ky) + oy;
        float px = (float)(x - 1 + kx) + ox;
        float fy0 = floorf(py), fx0 = floorf(px);
        float ly = py - fy0, lx = px - fx0;
        int y0 = (int)fy0, x0i = (int)fx0;
        float vy0 = ((unsigned)y0 < 128u) ? 1.0f : 0.0f;
        float vy1 = ((unsigned)(y0 + 1) < 128u) ? 1.0f : 0.0f;
        float vx0 = ((unsigned)x0i < 128u) ? 1.0f : 0.0f;
        float vx1 = ((unsigned)(x0i + 1) < 128u) ? 1.0f : 0.0f;
        int yc0 = min(max(y0, 0), 127), yc1 = min(max(y0 + 1, 0), 127);
        int xc0 = min(max(x0i, 0), 127), xc1 = min(max(x0i + 1, 0), 127);
        float pw00 = (1.0f - ly) * (1.0f - lx) * m * vy0 * vx0;
        float pw01 = (1.0f - ly) * lx * m * vy0 * vx1;
        float pw10 = ly * (1.0f - lx) * m * vy1 * vx0;
        float pw11 = ly * lx * m * vy1 * vx1;
        int xr = min(xc0, 126);
        int s0 = xc0 - xr, s1 = xc1 - xr;
        float ax = (s0 ? 0.0f : pw00) + (s1 ? 0.0f : pw01);
        float ay = (s0 ? pw00 : 0.0f) + (s1 ? pw01 : 0.0f);
        float bx = (s0 ? 0.0f : pw10) + (s1 ? 0.0f : pw11);
        float by = (s0 ? pw10 : 0.0f) + (s1 ? pw11 : 0.0f);
        int a_lo = yc0 * 128 + xr;
        int a_hi = yc1 * 128 + xr;
        const float* bp = fub + (size_t)(g * 16) * HWs;
        #pragma unroll
        for (int half = 0; half < 2; ++half) {
            bf16x8 ov;
            #pragma unroll
            for (int q = 0; q < 2; ++q) {
                f32x2 ra[4], rb[4];
                #pragma unroll
                for (int c = 0; c < 4; ++c) {
                    const float* p = bp + (size_t)(half * 8 + q * 4 + c) * HWs;
                    ra[c] = *(const f32x2*)(p + a_lo);
                    rb[c] = *(const f32x2*)(p + a_hi);
                }
                #pragma unroll
                for (int c = 0; c < 4; ++c) {
                    float v = ax * ra[c][0] + ay * ra[c][1] + bx * rb[c][0] + by * rb[c][1];
                    ov[q * 4 + c] = (bf16_t)v;
                }
            }
            *(bf16x8*)&val[gl][lane][tap * 16 + half * 8] = ov;
        }
    };

    for (int gc = 0; gc < 4; ++gc) {
        // unit indices for this wave: u0=w, u1=w+8, u2=w+16 (only waves 0,1)
        int g0 = gc * 2, tap0 = w;            // u0: gl=0
        int u1gl = (w + 8) / 9, u1tap = (w + 8) % 9;
        int u1g = gc * 2 + u1gl;
        int u2tap = w + 7;
        int u2g = gc * 2 + 1;

        // issue ALL om param loads up front (one latency for the interval)
        float oy0 = omb[(size_t)(g0 * 18 + tap0 * 2) * HWs + sp];
        float ox0 = omb[(size_t)(g0 * 18 + tap0 * 2 + 1) * HWs + sp];
        float m0  = omb[(size_t)(144 + g0 * 9 + tap0) * HWs + sp];
        float oy1 = omb[(size_t)(u1g * 18 + u1tap * 2) * HWs + sp];
        float ox1 = omb[(size_t)(u1g * 18 + u1tap * 2 + 1) * HWs + sp];
        float m1  = omb[(size_t)(144 + u1g * 9 + u1tap) * HWs + sp];
        float oy2 = 0.f, ox2 = 0.f, m2 = 0.f;
        if (w < 2) {
            oy2 = omb[(size_t)(u2g * 18 + u2tap * 2) * HWs + sp];
            ox2 = omb[(size_t)(u2g * 18 + u2tap * 2 + 1) * HWs + sp];
            m2  = omb[(size_t)(144 + u2g * 9 + u2tap) * HWs + sp];
        }

        process_unit(0, g0, tap0, oy0, ox0, m0);
        process_unit(u1gl, u1g, u1tap, oy1, ox1, m1);
        if (w < 2) process_unit(1, u2g, u2tap, oy2, ox2, m2);
        __syncthreads();
        #pragma unroll
        for (int gl = 0; gl < 2; ++gl) {
            int g = gc * 2 + gl;
            #pragma unroll
            for (int ks = 0; ks < 5; ++ks) {
                bf16x8 af = *((const bf16x8*)wpd + (((g * 5 + ks) * 8 + w) * 64 + lane));
                #pragma unroll
                for (int pi = 0; pi < 4; ++pi) {
                    bf16x8 bfr = *(const bf16x8*)&val[gl][pi * 16 + (lane & 15)][ks * 32 + ((lane >> 4) << 3)];
                    acc[pi] = __builtin_amdgcn_mfma_f32_16x16x32_bf16(af, bfr, acc[pi], 0, 0, 0);
                }
            }
        }
        __syncthreads();
    }
    #pragma unroll
    for (int j = 0; j < 4; ++j) {
        int o = w * 16 + ((lane >> 4) << 2) + j;
        float bv = bdcn[o];
        size_t base = (size_t)(b * 128 + o) * HWs + pos0 + (lane & 15);
        #pragma unroll
        for (int pi = 0; pi < 4; ++pi) {
            float v = fmaxf(acc[pi][j] + bv, 0.0f) + fl[base + pi * 16];
            outp[base + pi * 16] = v;
        }
    }
}

extern "C" void kernel_launch(void* const* d_in, const int* in_sizes, int n_in,
                              void* d_out, int out_size, void* d_ws, size_t ws_size,
                              hipStream_t stream) {
    const float* feat_l = (const float*)d_in[0];
    const float* feat_s = (const float*)d_in[1];
    const float* W_off  = (const float*)d_in[2];
    const float* W_om   = (const float*)d_in[3];
    const float* b_om   = (const float*)d_in[4];
    const float* W_dcn  = (const float*)d_in[5];
    const float* b_dcn  = (const float*)d_in[6];
    float* out = (float*)d_out;
    float* ws = (float*)d_ws;

    float* feat_up = ws;                        // 8,388,608 f
    float* offs    = ws + 8388608;              // 8,388,608 f
    float* om      = ws + 16777216;             // 14,155,776 f
    bf16_t* wpack1 = (bf16_t*)(ws + 30932992);  // 32,768 bf16
    bf16_t* wpack  = (bf16_t*)(ws + 30949376);  // 294,912 bf16
    bf16_t* wpdcn  = (bf16_t*)(ws + 31096832);  // 163,840 bf16

    k_prep<<<240, 256, 0, stream>>>(W_off, W_om, W_dcn, wpack1, wpack, wpdcn);
    k_upsample<<<32768, 256, 0, stream>>>(feat_s, feat_up);
    k_conv1m<<<1024, 256, 0, stream>>>(feat_l, feat_up, wpack1, offs);
    k_conv3m<<<1024, 256, 0, stream>>>(offs, wpack, b_om, om);
    k_dcn<<<1024, 512, 0, stream>>>(feat_up, om, wpdcn, b_dcn, feat_l, out);
}

// Round 9
// 349.146 us; speedup vs baseline: 1.3988x; 1.1484x over previous
//
#include <hip/hip_runtime.h>
#include <hip/hip_bf16.h>
#include <math.h>

#define BB 4
#define CC 128
#define HH 128
#define WW 128
#define HWs 16384
#define GG 8
#define OMCH 216

typedef __bf16 bf16_t;
typedef bf16_t bf16x8 __attribute__((ext_vector_type(8)));
typedef float f32x4 __attribute__((ext_vector_type(4)));
typedef float f32x2 __attribute__((ext_vector_type(2), aligned(4)));

// ---------------- prep: weight rearrange ----------------
__global__ __launch_bounds__(256) void k_prep(const float* __restrict__ W_off,
                                              const float* __restrict__ W_om,
                                              const float* __restrict__ W_dcn,
                                              bf16_t* __restrict__ wpack1,
                                              bf16_t* __restrict__ wpack,
                                              bf16_t* __restrict__ wpdcn) {
    int idx = blockIdx.x * 256 + threadIdx.x;
    if (idx < 4096) {
        int j = idx;
        int lane = j & 63;
        int rest = j >> 6;       // 0..63
        int ot = rest & 7;
        int ks = rest >> 3;      // 0..7
        int o = ot * 16 + (lane & 15);
        int cbase = ks * 32 + ((lane >> 4) << 3);
        bf16x8 v;
        #pragma unroll
        for (int r = 0; r < 8; ++r) v[r] = (bf16_t)W_off[o * 256 + cbase + r];
        *((bf16x8*)wpack1 + j) = v;
    } else if (idx < 4096 + 36864) {
        int j = idx - 4096;
        int lane = j & 63;
        int rest = j >> 6;       // 0..575
        int ot = rest & 15;
        int ks = rest >> 4;      // 0..35
        int cblk = ks / 9, tap = ks % 9;
        int o = ot * 16 + (lane & 15);
        int cbase = cblk * 32 + ((lane >> 4) << 3);
        bf16x8 v;
        #pragma unroll
        for (int r = 0; r < 8; ++r) {
            float x = (o < OMCH) ? W_om[((o * 128 + cbase + r) * 9) + tap] : 0.0f;
            v[r] = (bf16_t)x;
        }
        *((bf16x8*)wpack + j) = v;
    } else if (idx < 4096 + 36864 + 20480) {
        int j = idx - 40960;
        int lane = j & 63;
        int rest = j >> 6;       // 0..319
        int ot = rest & 7;
        int gks = rest >> 3;     // 0..39
        int g = gks / 5, ks = gks % 5;
        int o = ot * 16 + (lane & 15);
        int Kbase = ks * 32 + ((lane >> 4) << 3);
        bf16x8 v;
        #pragma unroll
        for (int r = 0; r < 8; ++r) {
            int K = Kbase + r;
            float x = 0.0f;
            if (K < 144) {
                int tap = K >> 4, cpp = K & 15;
                x = W_dcn[((o * 128) + g * 16 + cpp) * 9 + tap];
            }
            v[r] = (bf16_t)x;
        }
        *((bf16x8*)wpdcn + j) = v;
    }
}

// ---------------- bilinear 2x upsample ----------------
__global__ __launch_bounds__(256) void k_upsample(const float* __restrict__ fs,
                                                  float* __restrict__ fu) {
    int idx = blockIdx.x * 256 + threadIdx.x;
    int x = idx & 127, y = (idx >> 7) & 127, bc = idx >> 14;
    int j = y >> 1, i = x >> 1;
    int ya, yb; float wya, wyb;
    if (y & 1) { ya = j; yb = (j < 63) ? j + 1 : 63; wya = 0.75f; wyb = 0.25f; }
    else       { ya = (j > 0) ? j - 1 : 0; yb = j;   wya = 0.25f; wyb = 0.75f; }
    int xa, xb; float wxa, wxb;
    if (x & 1) { xa = i; xb = (i < 63) ? i + 1 : 63; wxa = 0.75f; wxb = 0.25f; }
    else       { xa = (i > 0) ? i - 1 : 0; xb = i;   wxa = 0.25f; wxb = 0.75f; }
    const float* p = fs + (size_t)bc * 4096;
    float v = wya * (wxa * p[ya * 64 + xa] + wxb * p[ya * 64 + xb])
            + wyb * (wxa * p[yb * 64 + xa] + wxb * p[yb * 64 + xb]);
    fu[idx] = v;
}

// ---------------- 1x1 conv via MFMA ----------------
#define X1LD 264
__global__ __launch_bounds__(256) void k_conv1m(const float* __restrict__ fl,
                                                const float* __restrict__ fu,
                                                const bf16_t* __restrict__ wp1,
                                                float* __restrict__ outp) {
    __shared__ __align__(16) bf16_t X[64][X1LD];
    int t = threadIdx.x, lane = t & 63, w = t >> 6;
    int b = blockIdx.x >> 8;
    int pos0 = (blockIdx.x & 255) << 6;
    f32x4 acc[2][4];
    #pragma unroll
    for (int i = 0; i < 2; ++i)
        #pragma unroll
        for (int j = 0; j < 4; ++j)
            acc[i][j] = (f32x4){0.f, 0.f, 0.f, 0.f};
    #pragma unroll 4
    for (int it = 0; it < 32; ++it) {
        int cp = it * 4 + w;
        int c = cp * 2;
        float v0, v1;
        if (c < 128) {
            size_t gb = (size_t)(b * 128 + c) * HWs + pos0 + lane;
            v0 = fl[gb]; v1 = fl[gb + HWs];
        } else {
            size_t gb = (size_t)(b * 128 + (c - 128)) * HWs + pos0 + lane;
            v0 = 2.0f * fu[gb]; v1 = 2.0f * fu[gb + HWs];
        }
        X[lane][c] = (bf16_t)v0;
        X[lane][c + 1] = (bf16_t)v1;
    }
    __syncthreads();
    #pragma unroll
    for (int ks = 0; ks < 8; ++ks) {
        bf16x8 af[2], bfr[4];
        const bf16x8* wp = (const bf16x8*)wp1 + ((ks * 8 + w * 2) * 64 + lane);
        af[0] = wp[0];
        af[1] = wp[64];
        #pragma unroll
        for (int pi = 0; pi < 4; ++pi)
            bfr[pi] = *(const bf16x8*)&X[pi * 16 + (lane & 15)][ks * 32 + ((lane >> 4) << 3)];
        #pragma unroll
        for (int oi = 0; oi < 2; ++oi)
            #pragma unroll
            for (int pi = 0; pi < 4; ++pi)
                acc[oi][pi] = __builtin_amdgcn_mfma_f32_16x16x32_bf16(af[oi], bfr[pi], acc[oi][pi], 0, 0, 0);
    }
    #pragma unroll
    for (int oi = 0; oi < 2; ++oi) {
        int obase = (w * 2 + oi) * 16 + ((lane >> 4) << 2);
        #pragma unroll
        for (int j = 0; j < 4; ++j) {
            int o = obase + j;
            size_t ob = (size_t)(b * 128 + o) * HWs + pos0 + (lane & 15);
            #pragma unroll
            for (int pi = 0; pi < 4; ++pi)
                outp[ob + pi * 16] = acc[oi][pi][j];
        }
    }
}

// ---------------- 3x3 conv via MFMA ----------------
#define X3LD 40
__global__ __launch_bounds__(256) void k_conv3m(const float* __restrict__ A,
                                                const bf16_t* __restrict__ wpack,
                                                const float* __restrict__ bom,
                                                float* __restrict__ om) {
    __shared__ __align__(16) bf16_t Xs[3 * 66 * X3LD];
    int t = threadIdx.x;
    int lane = t & 63, w = t >> 6;
    int b = blockIdx.x >> 8;
    int pos0 = (blockIdx.x & 255) << 6;
    int y = pos0 >> 7, x0 = pos0 & 127;
    f32x4 acc[4][4];
    #pragma unroll
    for (int i = 0; i < 4; ++i)
        #pragma unroll
        for (int j = 0; j < 4; ++j)
            acc[i][j] = (f32x4){0.f, 0.f, 0.f, 0.f};

    for (int cblk = 0; cblk < 4; ++cblk) {
        __syncthreads();
        for (int id = t; id < 3168; id += 256) {
            int col = id % 66;
            int rest = id / 66;
            int dy = rest % 3;
            int cp = rest / 3;
            int gy = y - 1 + dy, gx = x0 - 1 + col;
            float v0 = 0.f, v1 = 0.f;
            if ((unsigned)gy < 128u && (unsigned)gx < 128u) {
                size_t gb = ((size_t)(b * 128 + cblk * 32 + cp * 2) * 128 + gy) * 128 + gx;
                v0 = A[gb];
                v1 = A[gb + HWs];
            }
            int le = (dy * 66 + col) * X3LD + cp * 2;
            Xs[le] = (bf16_t)v0;
            Xs[le + 1] = (bf16_t)v1;
        }
        __syncthreads();
        #pragma unroll
        for (int tap = 0; tap < 9; ++tap) {
            const int ky = tap / 3, kx = tap % 3;
            bf16x8 af[4], bfr[4];
            const bf16x8* wp = (const bf16x8*)wpack + ((size_t)((cblk * 9 + tap) * 16 + w * 4) * 64 + lane);
            #pragma unroll
            for (int oi = 0; oi < 4; ++oi) af[oi] = wp[oi * 64];
            #pragma unroll
            for (int pi = 0; pi < 4; ++pi) {
                int colb = pi * 16 + (lane & 15) + kx;
                bfr[pi] = *(const bf16x8*)&Xs[(ky * 66 + colb) * X3LD + ((lane >> 4) << 3)];
            }
            #pragma unroll
            for (int oi = 0; oi < 4; ++oi)
                #pragma unroll
                for (int pi = 0; pi < 4; ++pi)
                    acc[oi][pi] = __builtin_amdgcn_mfma_f32_16x16x32_bf16(af[oi], bfr[pi], acc[oi][pi], 0, 0, 0);
        }
    }
    #pragma unroll
    for (int oi = 0; oi < 4; ++oi) {
        int obase = (w * 4 + oi) * 16 + ((lane >> 4) << 2);
        #pragma unroll
        for (int j = 0; j < 4; ++j) {
            int o = obase + j;
            if (o < OMCH) {
                float bv = bom[o];
                size_t ob = (size_t)(b * OMCH + o) * HWs + pos0 + (lane & 15);
                #pragma unroll
                for (int pi = 0; pi < 4; ++pi) {
                    float v = acc[oi][pi][j] + bv;
                    if (o >= 144) v = 1.0f / (1.0f + expf(-v));
                    om[ob + pi * 16] = v;
                }
            }
        }
    }
}

// ---------------- DCNv2 via MFMA + relu + residual ----------------
// 512 threads = 8 waves, 2 groups per barrier interval (18 units over 8 waves).
// __launch_bounds__(512,4): 128-VGPR budget -> no scratch spill (the round-6/8
// spill traced to the 85-reg cap of (512,6); occupancy was 50% either way).
// Next interval's om params are preloaded into named scalars before the
// barrier so their latency hides under the MFMA phase.
__global__ __launch_bounds__(512, 4) void k_dcn(const float* __restrict__ fu,
                                                const float* __restrict__ om,
                                                const bf16_t* __restrict__ wpd,
                                                const float* __restrict__ bdcn,
                                                const float* __restrict__ fl,
                                                float* __restrict__ outp) {
    __shared__ __align__(16) bf16_t val[2][64][168];
    int t = threadIdx.x;
    int lane = t & 63, w = t >> 6;           // wave 0..7
    int b = blockIdx.x >> 8;
    int pos0 = (blockIdx.x & 255) << 6;
    int y = pos0 >> 7, x0 = pos0 & 127;
    f32x4 acc[4];
    #pragma unroll
    for (int j = 0; j < 4; ++j) acc[j] = (f32x4){0.f, 0.f, 0.f, 0.f};
    for (int id = t; id < 2 * 64 * 24; id += 512) {
        int bufg = id / 1536, r = id % 1536;
        val[bufg][r / 24][144 + (r % 24)] = (bf16_t)0.0f;
    }

    const float* omb = om + (size_t)b * OMCH * HWs;
    const float* fub = fu + (size_t)b * 128 * HWs;
    size_t sp = (size_t)y * 128 + x0 + lane;

    // unit descriptors for this wave (fixed over gc):
    const int u1gl = (w + 8) / 9, u1tap = (w + 8) % 9;
    const int u2tap = w + 7;                 // only for w<2, gl=1

    auto process_unit = [&](int gl, int g, int tap, float oy, float ox, float m)
        __attribute__((always_inline)) {
        int ky = tap / 3, kx = tap % 3;
        int x = x0 + lane;
        float py = (float)(y - 1 + ky) + oy;
        float px = (float)(x - 1 + kx) + ox;
        float fy0 = floorf(py), fx0 = floorf(px);
        float ly = py - fy0, lx = px - fx0;
        int y0 = (int)fy0, x0i = (int)fx0;
        float vy0 = ((unsigned)y0 < 128u) ? 1.0f : 0.0f;
        float vy1 = ((unsigned)(y0 + 1) < 128u) ? 1.0f : 0.0f;
        float vx0 = ((unsigned)x0i < 128u) ? 1.0f : 0.0f;
        float vx1 = ((unsigned)(x0i + 1) < 128u) ? 1.0f : 0.0f;
        int yc0 = min(max(y0, 0), 127), yc1 = min(max(y0 + 1, 0), 127);
        int xc0 = min(max(x0i, 0), 127), xc1 = min(max(x0i + 1, 0), 127);
        float pw00 = (1.0f - ly) * (1.0f - lx) * m * vy0 * vx0;
        float pw01 = (1.0f - ly) * lx * m * vy0 * vx1;
        float pw10 = ly * (1.0f - lx) * m * vy1 * vx0;
        float pw11 = ly * lx * m * vy1 * vx1;
        int xr = min(xc0, 126);
        int s0 = xc0 - xr, s1 = xc1 - xr;
        float ax = (s0 ? 0.0f : pw00) + (s1 ? 0.0f : pw01);
        float ay = (s0 ? pw00 : 0.0f) + (s1 ? pw01 : 0.0f);
        float bx = (s0 ? 0.0f : pw10) + (s1 ? 0.0f : pw11);
        float by = (s0 ? pw10 : 0.0f) + (s1 ? pw11 : 0.0f);
        int a_lo = yc0 * 128 + xr;
        int a_hi = yc1 * 128 + xr;
        const float* bp = fub + (size_t)(g * 16) * HWs;
        #pragma unroll
        for (int half = 0; half < 2; ++half) {
            bf16x8 ov;
            #pragma unroll
            for (int q = 0; q < 2; ++q) {
                f32x2 ra[4], rb[4];
                #pragma unroll
                for (int c = 0; c < 4; ++c) {
                    const float* p = bp + (size_t)(half * 8 + q * 4 + c) * HWs;
                    ra[c] = *(const f32x2*)(p + a_lo);
                    rb[c] = *(const f32x2*)(p + a_hi);
                }
                #pragma unroll
                for (int c = 0; c < 4; ++c) {
                    float v = ax * ra[c][0] + ay * ra[c][1] + bx * rb[c][0] + by * rb[c][1];
                    ov[q * 4 + c] = (bf16_t)v;
                }
            }
            *(bf16x8*)&val[gl][lane][tap * 16 + half * 8] = ov;
        }
    };

    // preload params for gc=0
    float oy0, ox0, m0, oy1, ox1, m1, oy2 = 0.f, ox2 = 0.f, m2 = 0.f;
    {
        int g0 = 0, u1g = u1gl, u2g = 1;
        oy0 = omb[(size_t)(g0 * 18 + w * 2) * HWs + sp];
        ox0 = omb[(size_t)(g0 * 18 + w * 2 + 1) * HWs + sp];
        m0  = omb[(size_t)(144 + g0 * 9 + w) * HWs + sp];
        oy1 = omb[(size_t)(u1g * 18 + u1tap * 2) * HWs + sp];
        ox1 = omb[(size_t)(u1g * 18 + u1tap * 2 + 1) * HWs + sp];
        m1  = omb[(size_t)(144 + u1g * 9 + u1tap) * HWs + sp];
        if (w < 2) {
            oy2 = omb[(size_t)(u2g * 18 + u2tap * 2) * HWs + sp];
            ox2 = omb[(size_t)(u2g * 18 + u2tap * 2 + 1) * HWs + sp];
            m2  = omb[(size_t)(144 + u2g * 9 + u2tap) * HWs + sp];
        }
    }

    for (int gc = 0; gc < 4; ++gc) {
        process_unit(0, gc * 2, w, oy0, ox0, m0);
        process_unit(u1gl, gc * 2 + u1gl, u1tap, oy1, ox1, m1);
        if (w < 2) process_unit(1, gc * 2 + 1, u2tap, oy2, ox2, m2);
        // preload next interval's params; latency hides under the MFMA phase
        if (gc < 3) {
            int g0 = (gc + 1) * 2;
            int u1g = g0 + u1gl, u2g = g0 + 1;
            oy0 = omb[(size_t)(g0 * 18 + w * 2) * HWs + sp];
            ox0 = omb[(size_t)(g0 * 18 + w * 2 + 1) * HWs + sp];
            m0  = omb[(size_t)(144 + g0 * 9 + w) * HWs + sp];
            oy1 = omb[(size_t)(u1g * 18 + u1tap * 2) * HWs + sp];
            ox1 = omb[(size_t)(u1g * 18 + u1tap * 2 + 1) * HWs + sp];
            m1  = omb[(size_t)(144 + u1g * 9 + u1tap) * HWs + sp];
            if (w < 2) {
                oy2 = omb[(size_t)(u2g * 18 + u2tap * 2) * HWs + sp];
                ox2 = omb[(size_t)(u2g * 18 + u2tap * 2 + 1) * HWs + sp];
                m2  = omb[(size_t)(144 + u2g * 9 + u2tap) * HWs + sp];
            }
        }
        __syncthreads();
        #pragma unroll
        for (int gl = 0; gl < 2; ++gl) {
            int g = gc * 2 + gl;
            #pragma unroll
            for (int ks = 0; ks < 5; ++ks) {
                bf16x8 af = *((const bf16x8*)wpd + (((g * 5 + ks) * 8 + w) * 64 + lane));
                #pragma unroll
                for (int pi = 0; pi < 4; ++pi) {
                    bf16x8 bfr = *(const bf16x8*)&val[gl][pi * 16 + (lane & 15)][ks * 32 + ((lane >> 4) << 3)];
                    acc[pi] = __builtin_amdgcn_mfma_f32_16x16x32_bf16(af, bfr, acc[pi], 0, 0, 0);
                }
            }
        }
        __syncthreads();
    }
    #pragma unroll
    for (int j = 0; j < 4; ++j) {
        int o = w * 16 + ((lane >> 4) << 2) + j;
        float bv = bdcn[o];
        size_t base = (size_t)(b * 128 + o) * HWs + pos0 + (lane & 15);
        #pragma unroll
        for (int pi = 0; pi < 4; ++pi) {
            float v = fmaxf(acc[pi][j] + bv, 0.0f) + fl[base + pi * 16];
            outp[base + pi * 16] = v;
        }
    }
}

extern "C" void kernel_launch(void* const* d_in, const int* in_sizes, int n_in,
                              void* d_out, int out_size, void* d_ws, size_t ws_size,
                              hipStream_t stream) {
    const float* feat_l = (const float*)d_in[0];
    const float* feat_s = (const float*)d_in[1];
    const float* W_off  = (const float*)d_in[2];
    const float* W_om   = (const float*)d_in[3];
    const float* b_om   = (const float*)d_in[4];
    const float* W_dcn  = (const float*)d_in[5];
    const float* b_dcn  = (const float*)d_in[6];
    float* out = (float*)d_out;
    float* ws = (float*)d_ws;

    float* feat_up = ws;                        // 8,388,608 f
    float* offs    = ws + 8388608;              // 8,388,608 f
    float* om      = ws + 16777216;             // 14,155,776 f
    bf16_t* wpack1 = (bf16_t*)(ws + 30932992);  // 32,768 bf16
    bf16_t* wpack  = (bf16_t*)(ws + 30949376);  // 294,912 bf16
    bf16_t* wpdcn  = (bf16_t*)(ws + 31096832);  // 163,840 bf16

    k_prep<<<240, 256, 0, stream>>>(W_off, W_om, W_dcn, wpack1, wpack, wpdcn);
    k_upsample<<<32768, 256, 0, stream>>>(feat_s, feat_up);
    k_conv1m<<<1024, 256, 0, stream>>>(feat_l, feat_up, wpack1, offs);
    k_conv3m<<<1024, 256, 0, stream>>>(offs, wpack, b_om, om);
    k_dcn<<<1024, 512, 0, stream>>>(feat_up, om, wpdcn, b_dcn, feat_l, out);
}